// Round 2
// baseline (574.870 us; speedup 1.0000x reference)
//
#include <hip/hip_runtime.h>
#include <hip/hip_bf16.h>

#define DIM 128
#define KNB 16
#define NPB 32   // nodes per block, phase 1

__device__ __forceinline__ unsigned short bf16bits(float f) {
    union { float f; unsigned u; } v; v.f = f;
    unsigned r = v.u + 0x7fffu + ((v.u >> 16) & 1u);   // round-nearest-even
    return (unsigned short)(r >> 16);
}
__device__ __forceinline__ float bflo(unsigned u) { return __uint_as_float(u << 16); }
__device__ __forceinline__ float bfhi(unsigned u) { return __uint_as_float(u & 0xffff0000u); }

// ---------------------------------------------------------------------------
// Phase 1: A[n][h] = b1[h] + lat[n]·W1[:128][h]   (f32, 51.2 MB)
//          P[n]    = [ bf16(lat[n]·W1[128:][h]) | bf16(lat[n]) ]  (256 bf16/row)
// 256 threads = 256 output columns; 32 nodes/block. lat read via wave-uniform
// scalar loads (SGPR), W1 column chunk in VGPRs -> pure v_fmac inner loop.
// ---------------------------------------------------------------------------
__global__ __launch_bounds__(256) void na_precompute_AB(
    const float* __restrict__ lat, const float* __restrict__ W1,
    const float* __restrict__ b1, float* __restrict__ A,
    unsigned short* __restrict__ P, int nNodes)
{
    const int t    = threadIdx.x;
    const int h    = t & 127;
    const int isB  = t >> 7;
    const int base = blockIdx.x * NPB;

    const float* wbase = W1 + (size_t)(isB ? DIM : 0) * DIM + h;

    float acc[NPB];
#pragma unroll
    for (int i = 0; i < NPB; ++i) acc[i] = 0.f;

    for (int kc = 0; kc < 4; ++kc) {
        float w[32];
#pragma unroll
        for (int dd = 0; dd < 32; ++dd)
            w[dd] = wbase[(size_t)(kc * 32 + dd) * DIM];
#pragma unroll
        for (int i = 0; i < NPB; ++i) {
            int n = base + i; if (n >= nNodes) n = nNodes - 1;
            const float* lrow = lat + (size_t)n * DIM + kc * 32;  // uniform -> s_load
#pragma unroll
            for (int dd = 0; dd < 32; ++dd)
                acc[i] += lrow[dd] * w[dd];
        }
    }

    if (isB) {
#pragma unroll
        for (int i = 0; i < NPB; ++i) {
            int n = base + i;
            if (n < nNodes) P[(size_t)n * 256 + h] = bf16bits(acc[i]);
        }
    } else {
        const float bias = b1[h];
#pragma unroll
        for (int i = 0; i < NPB; ++i) {
            int n = base + i;
            if (n < nNodes) A[(size_t)n * DIM + h] = acc[i] + bias;
        }
    }

    // lat half of P (bf16 copy), 32 nodes x 128 dims by all 256 threads
#pragma unroll
    for (int i2 = 0; i2 < 16; ++i2) {
        int idx = i2 * 256 + t;
        int nl = idx >> 7, d = idx & 127;
        int n = base + nl;
        if (n < nNodes)
            P[(size_t)n * 256 + 128 + d] = bf16bits(lat[(size_t)n * DIM + d]);
    }
}

// ---------------------------------------------------------------------------
// Phase 2: one wave per node; lane l owns dims (2l, 2l+1).
// Gathers: P32[j*128 + l] (B pair) and P32[j*128 + 64 + l] (lat pair) --
// each a single fully-coalesced 256B request; 512B per (n,k) pair total.
// All 32 gathers issued before score math for max memory-level parallelism.
// ---------------------------------------------------------------------------
__global__ __launch_bounds__(256) void na_score_agg(
    const int* __restrict__ nbr, const float* __restrict__ A,
    const unsigned int* __restrict__ P32, const float* __restrict__ W2,
    float* __restrict__ out, int nNodes)
{
    const int wave = threadIdx.x >> 6;
    const int lane = threadIdx.x & 63;
    const int n = blockIdx.x * 4 + wave;
    if (n >= nNodes) return;

    const float2 a  = *(const float2*)(A  + (size_t)n * DIM + 2 * lane);
    const float2 w2 = *(const float2*)(W2 + 2 * lane);
    const int jl = nbr[n * KNB + (lane & 15)];

    unsigned bB[KNB], bL[KNB];
#pragma unroll
    for (int k = 0; k < KNB; ++k) {
        int j = __shfl(jl, k);
        const unsigned* Pj = P32 + (size_t)j * 128;
        bB[k] = Pj[lane];
        bL[k] = Pj[64 + lane];
    }

    float s[KNB];
#pragma unroll
    for (int k = 0; k < KNB; ++k) {
        float h0 = fmaxf(a.x + bflo(bB[k]), 0.f);
        float h1 = fmaxf(a.y + bfhi(bB[k]), 0.f);
        float p  = h0 * w2.x + h1 * w2.y;
#pragma unroll
        for (int off = 32; off; off >>= 1) p += __shfl_xor(p, off);
        s[k] = p;
    }

    float m = s[0];
#pragma unroll
    for (int k = 1; k < KNB; ++k) m = fmaxf(m, s[k]);
    float sum = 0.f;
#pragma unroll
    for (int k = 0; k < KNB; ++k) { s[k] = __expf(s[k] - m); sum += s[k]; }
    const float inv = 1.f / sum;

    float o0 = 0.f, o1 = 0.f;
#pragma unroll
    for (int k = 0; k < KNB; ++k) {
        o0 += s[k] * bflo(bL[k]);
        o1 += s[k] * bfhi(bL[k]);
    }

    float2 o; o.x = o0 * inv; o.y = o1 * inv;
    *(float2*)(out + (size_t)n * DIM + 2 * lane) = o;
}

// ---------------------------------------------------------------------------
// Fallback (workspace too small): direct computation, one wave/node.
// ---------------------------------------------------------------------------
__global__ __launch_bounds__(256) void na_naive(
    const float* __restrict__ lat, const int* __restrict__ nbr,
    const float* __restrict__ W1, const float* __restrict__ b1,
    const float* __restrict__ W2, float* __restrict__ out, int nNodes)
{
    const int wave = threadIdx.x >> 6;
    const int lane = threadIdx.x & 63;
    const int n = blockIdx.x * 4 + wave;
    if (n >= nNodes) return;

    const int d0 = lane, d1 = lane + 64;
    const float w20 = W2[d0];
    const float w21 = W2[d1];
    const float c0 = lat[(size_t)n * DIM + d0];
    const float c1 = lat[(size_t)n * DIM + d1];

    float a0 = b1[d0], a1 = b1[d1];
    for (int r = 0; r < DIM; ++r) {
        float cv = (r < 64) ? __shfl(c0, r) : __shfl(c1, r - 64);
        a0 += cv * W1[(size_t)r * DIM + d0];
        a1 += cv * W1[(size_t)r * DIM + d1];
    }

    const int jl = nbr[n * KNB + (lane & 15)];
    float s[KNB], nl0[KNB], nl1[KNB];

    for (int k = 0; k < KNB; ++k) {
        int j = __shfl(jl, k);
        float l0 = lat[(size_t)j * DIM + d0];
        float l1 = lat[(size_t)j * DIM + d1];
        nl0[k] = l0; nl1[k] = l1;
        float h0 = a0, h1 = a1;
        for (int r = 0; r < DIM; ++r) {
            float nv = (r < 64) ? __shfl(l0, r) : __shfl(l1, r - 64);
            h0 += nv * W1[(size_t)(DIM + r) * DIM + d0];
            h1 += nv * W1[(size_t)(DIM + r) * DIM + d1];
        }
        h0 = fmaxf(h0, 0.f);
        h1 = fmaxf(h1, 0.f);
        float p = h0 * w20 + h1 * w21;
#pragma unroll
        for (int off = 32; off; off >>= 1) p += __shfl_xor(p, off);
        s[k] = p;
    }

    float m = s[0];
#pragma unroll
    for (int k = 1; k < KNB; ++k) m = fmaxf(m, s[k]);
    float sum = 0.f;
#pragma unroll
    for (int k = 0; k < KNB; ++k) { s[k] = expf(s[k] - m); sum += s[k]; }
    float inv = 1.f / sum;

    float o0 = 0.f, o1 = 0.f;
#pragma unroll
    for (int k = 0; k < KNB; ++k) { o0 += s[k] * nl0[k]; o1 += s[k] * nl1[k]; }

    out[(size_t)n * DIM + d0] = o0 * inv;
    out[(size_t)n * DIM + d1] = o1 * inv;
}

extern "C" void kernel_launch(void* const* d_in, const int* in_sizes, int n_in,
                              void* d_out, int out_size, void* d_ws, size_t ws_size,
                              hipStream_t stream)
{
    const float* lat = (const float*)d_in[0];
    const int*   nbr = (const int*)  d_in[1];
    const float* W1  = (const float*)d_in[2];
    const float* b1  = (const float*)d_in[3];
    const float* W2  = (const float*)d_in[4];
    // d_in[5] = b2: shift-invariant under softmax, unused.
    float* out = (float*)d_out;

    const int nNodes = in_sizes[0] / DIM;  // 100000
    const size_t bytesA = (size_t)nNodes * DIM * sizeof(float);          // 51.2 MB
    const size_t bytesP = (size_t)nNodes * 256 * sizeof(unsigned short); // 51.2 MB

    if (ws_size >= bytesA + bytesP) {
        float* A = (float*)d_ws;
        unsigned short* P = (unsigned short*)((char*)d_ws + bytesA);
        na_precompute_AB<<<(nNodes + NPB - 1) / NPB, 256, 0, stream>>>(lat, W1, b1, A, P, nNodes);
        na_score_agg<<<(nNodes + 3) / 4, 256, 0, stream>>>(nbr, A, (const unsigned int*)P, W2, out, nNodes);
    } else {
        na_naive<<<(nNodes + 3) / 4, 256, 0, stream>>>(lat, nbr, W1, b1, W2, out, nNodes);
    }
}

// Round 3
// 236.822 us; speedup vs baseline: 2.4274x; 2.4274x over previous
//
#include <hip/hip_runtime.h>
#include <hip/hip_bf16.h>

#define DIM 128
#define KNB 16

using fragAB = __attribute__((ext_vector_type(8))) short;   // 8 bf16 (4 VGPRs)
using f32x4  = __attribute__((ext_vector_type(4))) float;   // 4 fp32 acc

__device__ __forceinline__ unsigned short bf16bits(float f) {
    union { float f; unsigned u; } v; v.f = f;
    unsigned r = v.u + 0x7fffu + ((v.u >> 16) & 1u);   // round-nearest-even
    return (unsigned short)(r >> 16);
}
__device__ __forceinline__ float bflo(unsigned u) { return __uint_as_float(u << 16); }
__device__ __forceinline__ float bfhi(unsigned u) { return __uint_as_float(u & 0xffff0000u); }

// ---------------------------------------------------------------------------
// W1T pack: W1T[h'][d] (bf16, 256x128) where h'<128 -> W1[d][h'] (A-part),
// h'>=128 -> W1[128+d][h'-128] (B-part). B^T layout: contiguous-K B-frags.
// ---------------------------------------------------------------------------
__global__ __launch_bounds__(256) void na_w1t(
    const float* __restrict__ W1, unsigned short* __restrict__ W1T)
{
    int idx = blockIdx.x * 256 + threadIdx.x;   // 0..32767 = h'*128 + d
    int hp = idx >> 7, d = idx & 127;
    float v = (hp < DIM) ? W1[(size_t)d * DIM + hp]
                         : W1[(size_t)(DIM + d) * DIM + (hp - DIM)];
    W1T[idx] = bf16bits(v);
}

// ---------------------------------------------------------------------------
// Phase 1 (MFMA): per block 64 rows; wave w owns rows [mbase, mbase+16) and
// all 256 output cols (16 Ntiles). K=128 in 4 steps of 32.
//   A[n][h]       = b1[h] + lat[n] . W1top[:,h]      (f32)
//   P[n][0..128)  = bf16( lat[n] . W1bot[:,h] )
//   P[n][128..256)= bf16( lat[n] )
// A-frag: row = mbase+(lane&15), k = ks*32+(lane>>4)*8+[0..8)  (128B/row).
// B-frag: 16B contiguous from W1T (L1/L2-resident).
// C/D: col = lane&15, row = (lane>>4)*4 + reg   [m89-verified].
// ---------------------------------------------------------------------------
__global__ __launch_bounds__(256) void na_precompute_mfma(
    const float* __restrict__ lat, const unsigned short* __restrict__ W1T,
    const float* __restrict__ b1, float* __restrict__ A,
    unsigned short* __restrict__ P, int nNodes)
{
    const int wave = threadIdx.x >> 6;
    const int lane = threadIdx.x & 63;
    const int lg = lane >> 4, lr = lane & 15;
    const int mbase = blockIdx.x * 64 + wave * 16;

    f32x4 acc[16];
#pragma unroll
    for (int i = 0; i < 16; ++i) acc[i] = (f32x4){0.f, 0.f, 0.f, 0.f};

    int arow = mbase + lr; if (arow >= nNodes) arow = nNodes - 1;
    const float* aptr = lat + (size_t)arow * DIM + lg * 8;

#pragma unroll
    for (int ks = 0; ks < 4; ++ks) {
        f32x4 lo = *(const f32x4*)(aptr + ks * 32);
        f32x4 hi = *(const f32x4*)(aptr + ks * 32 + 4);
        fragAB af;
#pragma unroll
        for (int j = 0; j < 4; ++j) {
            af[j]     = (short)bf16bits(lo[j]);
            af[4 + j] = (short)bf16bits(hi[j]);
        }
#pragma unroll
        for (int nt = 0; nt < 16; ++nt) {
            const unsigned short* bp = W1T + (size_t)(nt * 16 + lr) * DIM + ks * 32 + lg * 8;
            fragAB bf = *(const fragAB*)bp;
            acc[nt] = __builtin_amdgcn_mfma_f32_16x16x32_bf16(af, bf, acc[nt], 0, 0, 0);
        }
    }

#pragma unroll
    for (int nt = 0; nt < 16; ++nt) {
        const int col = nt * 16 + lr;
#pragma unroll
        for (int r = 0; r < 4; ++r) {
            int row = mbase + lg * 4 + r;
            if (row >= nNodes) continue;
            float v = acc[nt][r];
            if (col < DIM) A[(size_t)row * DIM + col] = v + b1[col];
            else           P[(size_t)row * 256 + (col - DIM)] = bf16bits(v);
        }
    }

    // lat half of P: rows [blockIdx*64, +64)
    const int t = threadIdx.x;
    const int rbase = blockIdx.x * 64;
#pragma unroll
    for (int i = 0; i < 32; ++i) {
        int idx = i * 256 + t;          // 0..8191
        int nl = idx >> 7, d = idx & 127;
        int n = rbase + nl;
        if (n < nNodes)
            P[(size_t)n * 256 + DIM + d] = bf16bits(lat[(size_t)n * DIM + d]);
    }
}

// ---------------------------------------------------------------------------
// Phase 2: one wave per node; lane l owns dims (2l, 2l+1).
// Gathers P rows (512B each: B-half + lat-half bf16), fully coalesced.
// ---------------------------------------------------------------------------
__global__ __launch_bounds__(256) void na_score_agg(
    const int* __restrict__ nbr, const float* __restrict__ A,
    const unsigned int* __restrict__ P32, const float* __restrict__ W2,
    float* __restrict__ out, int nNodes)
{
    const int wave = threadIdx.x >> 6;
    const int lane = threadIdx.x & 63;
    const int n = blockIdx.x * 4 + wave;
    if (n >= nNodes) return;

    const float2 a  = *(const float2*)(A  + (size_t)n * DIM + 2 * lane);
    const float2 w2 = *(const float2*)(W2 + 2 * lane);
    const int jl = nbr[n * KNB + (lane & 15)];

    unsigned bB[KNB], bL[KNB];
#pragma unroll
    for (int k = 0; k < KNB; ++k) {
        int j = __shfl(jl, k);
        const unsigned* Pj = P32 + (size_t)j * 128;
        bB[k] = Pj[lane];
        bL[k] = Pj[64 + lane];
    }

    float s[KNB];
#pragma unroll
    for (int k = 0; k < KNB; ++k) {
        float h0 = fmaxf(a.x + bflo(bB[k]), 0.f);
        float h1 = fmaxf(a.y + bfhi(bB[k]), 0.f);
        float p  = h0 * w2.x + h1 * w2.y;
#pragma unroll
        for (int off = 32; off; off >>= 1) p += __shfl_xor(p, off);
        s[k] = p;
    }

    float m = s[0];
#pragma unroll
    for (int k = 1; k < KNB; ++k) m = fmaxf(m, s[k]);
    float sum = 0.f;
#pragma unroll
    for (int k = 0; k < KNB; ++k) { s[k] = __expf(s[k] - m); sum += s[k]; }
    const float inv = 1.f / sum;

    float o0 = 0.f, o1 = 0.f;
#pragma unroll
    for (int k = 0; k < KNB; ++k) {
        o0 += s[k] * bflo(bL[k]);
        o1 += s[k] * bfhi(bL[k]);
    }

    float2 o; o.x = o0 * inv; o.y = o1 * inv;
    *(float2*)(out + (size_t)n * DIM + 2 * lane) = o;
}

// ---------------------------------------------------------------------------
// Fallback (workspace too small): direct computation, one wave/node.
// ---------------------------------------------------------------------------
__global__ __launch_bounds__(256) void na_naive(
    const float* __restrict__ lat, const int* __restrict__ nbr,
    const float* __restrict__ W1, const float* __restrict__ b1,
    const float* __restrict__ W2, float* __restrict__ out, int nNodes)
{
    const int wave = threadIdx.x >> 6;
    const int lane = threadIdx.x & 63;
    const int n = blockIdx.x * 4 + wave;
    if (n >= nNodes) return;

    const int d0 = lane, d1 = lane + 64;
    const float w20 = W2[d0];
    const float w21 = W2[d1];
    const float c0 = lat[(size_t)n * DIM + d0];
    const float c1 = lat[(size_t)n * DIM + d1];

    float a0 = b1[d0], a1 = b1[d1];
    for (int r = 0; r < DIM; ++r) {
        float cv = (r < 64) ? __shfl(c0, r) : __shfl(c1, r - 64);
        a0 += cv * W1[(size_t)r * DIM + d0];
        a1 += cv * W1[(size_t)r * DIM + d1];
    }

    const int jl = nbr[n * KNB + (lane & 15)];
    float s[KNB], nl0[KNB], nl1[KNB];

    for (int k = 0; k < KNB; ++k) {
        int j = __shfl(jl, k);
        float l0 = lat[(size_t)j * DIM + d0];
        float l1 = lat[(size_t)j * DIM + d1];
        nl0[k] = l0; nl1[k] = l1;
        float h0 = a0, h1 = a1;
        for (int r = 0; r < DIM; ++r) {
            float nv = (r < 64) ? __shfl(l0, r) : __shfl(l1, r - 64);
            h0 += nv * W1[(size_t)(DIM + r) * DIM + d0];
            h1 += nv * W1[(size_t)(DIM + r) * DIM + d1];
        }
        h0 = fmaxf(h0, 0.f);
        h1 = fmaxf(h1, 0.f);
        float p = h0 * w20 + h1 * w21;
#pragma unroll
        for (int off = 32; off; off >>= 1) p += __shfl_xor(p, off);
        s[k] = p;
    }

    float m = s[0];
#pragma unroll
    for (int k = 1; k < KNB; ++k) m = fmaxf(m, s[k]);
    float sum = 0.f;
#pragma unroll
    for (int k = 0; k < KNB; ++k) { s[k] = expf(s[k] - m); sum += s[k]; }
    float inv = 1.f / sum;

    float o0 = 0.f, o1 = 0.f;
#pragma unroll
    for (int k = 0; k < KNB; ++k) { o0 += s[k] * nl0[k]; o1 += s[k] * nl1[k]; }

    out[(size_t)n * DIM + d0] = o0 * inv;
    out[(size_t)n * DIM + d1] = o1 * inv;
}

extern "C" void kernel_launch(void* const* d_in, const int* in_sizes, int n_in,
                              void* d_out, int out_size, void* d_ws, size_t ws_size,
                              hipStream_t stream)
{
    const float* lat = (const float*)d_in[0];
    const int*   nbr = (const int*)  d_in[1];
    const float* W1  = (const float*)d_in[2];
    const float* b1  = (const float*)d_in[3];
    const float* W2  = (const float*)d_in[4];
    // d_in[5] = b2: shift-invariant under softmax, unused.
    float* out = (float*)d_out;

    const int nNodes = in_sizes[0] / DIM;  // 100000
    const size_t bytesA = (size_t)nNodes * DIM * sizeof(float);          // 51.2 MB
    const size_t bytesP = (size_t)nNodes * 256 * sizeof(unsigned short); // 51.2 MB
    const size_t bytesW = 256 * DIM * sizeof(unsigned short);            // 64 KiB

    if (ws_size >= bytesA + bytesP + bytesW) {
        float* A = (float*)d_ws;
        unsigned short* P   = (unsigned short*)((char*)d_ws + bytesA);
        unsigned short* W1T = (unsigned short*)((char*)d_ws + bytesA + bytesP);
        na_w1t<<<128, 256, 0, stream>>>(W1, W1T);
        na_precompute_mfma<<<(nNodes + 63) / 64, 256, 0, stream>>>(lat, W1T, b1, A, P, nNodes);
        na_score_agg<<<(nNodes + 3) / 4, 256, 0, stream>>>(nbr, A, (const unsigned int*)P, W2, out, nNodes);
    } else {
        na_naive<<<(nNodes + 3) / 4, 256, 0, stream>>>(lat, nbr, W1, b1, W2, out, nNodes);
    }
}

// Round 4
// 202.207 us; speedup vs baseline: 2.8430x; 1.1712x over previous
//
#include <hip/hip_runtime.h>
#include <hip/hip_bf16.h>

#define DIM 128
#define KNB 16

using fragAB = __attribute__((ext_vector_type(8))) short;   // 8 bf16 (4 VGPRs)
using f32x4  = __attribute__((ext_vector_type(4))) float;   // 4 fp32 acc
using u32x4  = __attribute__((ext_vector_type(4))) unsigned int;

union frag_u { fragAB s; u32x4 u; };

__device__ __forceinline__ unsigned short bf16bits(float f) {
    union { float f; unsigned u; } v; v.f = f;
    unsigned r = v.u + 0x7fffu + ((v.u >> 16) & 1u);   // round-nearest-even
    return (unsigned short)(r >> 16);
}
__device__ __forceinline__ float bflo(unsigned u) { return __uint_as_float(u << 16); }
__device__ __forceinline__ float bfhi(unsigned u) { return __uint_as_float(u & 0xffff0000u); }

// ---------------------------------------------------------------------------
// W1T pack (bf16 B^T layout for MFMA B-frags) + W2 bf16.
// W1T[h'][d]: h'<128 -> W1[d][h'] (A-part), h'>=128 -> W1[128+d][h'-128] (B).
// ---------------------------------------------------------------------------
__global__ __launch_bounds__(256) void na_w1t(
    const float* __restrict__ W1, const float* __restrict__ W2,
    unsigned short* __restrict__ W1T, unsigned short* __restrict__ W2b)
{
    int idx = blockIdx.x * 256 + threadIdx.x;   // 0..32767 = h'*128 + d
    int hp = idx >> 7, d = idx & 127;
    float v = (hp < DIM) ? W1[(size_t)d * DIM + hp]
                         : W1[(size_t)(DIM + d) * DIM + (hp - DIM)];
    W1T[idx] = bf16bits(v);
    if (blockIdx.x == 0 && threadIdx.x < DIM) W2b[threadIdx.x] = bf16bits(W2[threadIdx.x]);
}

// ---------------------------------------------------------------------------
// Phase 1 (MFMA): block = 64 rows, wave = 16 rows x 256 cols (16 Ntiles).
//   Ab[n][h]      = bf16( b1[h] + lat[n]·W1top[:,h] )
//   P[n][0..128)  = bf16( lat[n]·W1bot[:,h] )
//   P[n][128..256)= bf16( lat[n] )        <- written from held A-frags (af),
//                                            no second read of lat.
// ---------------------------------------------------------------------------
__global__ __launch_bounds__(256) void na_precompute_mfma(
    const float* __restrict__ lat, const unsigned short* __restrict__ W1T,
    const float* __restrict__ b1, unsigned short* __restrict__ Ab,
    unsigned short* __restrict__ P, int nNodes)
{
    const int wave = threadIdx.x >> 6;
    const int lane = threadIdx.x & 63;
    const int lg = lane >> 4, lr = lane & 15;
    const int mbase = blockIdx.x * 64 + wave * 16;

    f32x4 acc[16];
#pragma unroll
    for (int i = 0; i < 16; ++i) acc[i] = (f32x4){0.f, 0.f, 0.f, 0.f};

    const int arow = mbase + lr;
    const bool avalid = arow < nNodes;
    const int arc = avalid ? arow : (nNodes - 1);
    const float* aptr = lat + (size_t)arc * DIM + lg * 8;

    fragAB af[4];
#pragma unroll
    for (int ks = 0; ks < 4; ++ks) {
        f32x4 lo = *(const f32x4*)(aptr + ks * 32);
        f32x4 hi = *(const f32x4*)(aptr + ks * 32 + 4);
#pragma unroll
        for (int j = 0; j < 4; ++j) {
            af[ks][j]     = (short)bf16bits(lo[j]);
            af[ks][4 + j] = (short)bf16bits(hi[j]);
        }
#pragma unroll
        for (int nt = 0; nt < 16; ++nt) {
            const unsigned short* bp = W1T + (size_t)(nt * 16 + lr) * DIM + ks * 32 + lg * 8;
            fragAB bf = *(const fragAB*)bp;
            acc[nt] = __builtin_amdgcn_mfma_f32_16x16x32_bf16(af[ks], bf, acc[nt], 0, 0, 0);
        }
    }

    // lat-half of P directly from af: 4 x 16B vector stores per lane
    if (avalid) {
        unsigned short* pl = P + (size_t)arow * 256 + DIM + lg * 8;
#pragma unroll
        for (int ks = 0; ks < 4; ++ks)
            *(fragAB*)(pl + ks * 32) = af[ks];
    }

    // A (bf16, +bias) and B halves from accumulators
#pragma unroll
    for (int nt = 0; nt < 16; ++nt) {
        const int col = nt * 16 + lr;
        const float bias = (nt < 8) ? b1[col] : 0.f;
#pragma unroll
        for (int r = 0; r < 4; ++r) {
            int row = mbase + lg * 4 + r;
            if (row >= nNodes) continue;
            float v = acc[nt][r];
            if (nt < 8) Ab[(size_t)row * DIM + col] = bf16bits(v + bias);
            else        P[(size_t)row * 256 + (col - DIM)] = bf16bits(v);
        }
    }
}

// ---------------------------------------------------------------------------
// Phase 2: one wave per node. Scores via MFMA:
//   H = relu(A[n] + B[j_k])  (16 x 128, bf16, built in-register)
//   S = H · W2               (one mfma_16x16x32 chain, W2 replicated over
//                             all 16 B-columns -> every lane holds 4 scores,
//                             quads replicated across lr)
// exp computed 4/lane, then butterfly-distributed (12 shfl). Aggregation:
// lane owns dims (2l,2l+1), 16 bf16-pair gathers of lat rows.
// ---------------------------------------------------------------------------
__global__ __launch_bounds__(256) void na_score_agg(
    const int* __restrict__ nbr, const unsigned short* __restrict__ Ab,
    const unsigned short* __restrict__ Pu, const unsigned int* __restrict__ P32,
    const unsigned short* __restrict__ W2b, float* __restrict__ out, int nNodes)
{
    const int wave = threadIdx.x >> 6;
    const int lane = threadIdx.x & 63;
    const int lg = lane >> 4, lr = lane & 15;
    const int n = blockIdx.x * 4 + wave;
    if (n >= nNodes) return;

    const int jl = nbr[n * KNB + lr];          // lane's neighbor (k = lr)

    // B-half gathers: lane reads 16B of row j_lr per ks (A-frag layout for H)
    frag_u fB[4];
    const unsigned short* Pj = Pu + (size_t)jl * 256;
#pragma unroll
    for (int ks = 0; ks < 4; ++ks)
        fB[ks].s = *(const fragAB*)(Pj + ks * 32 + lg * 8);

    // lat-half gathers: lane owns dims (2l,2l+1), loop over k
    unsigned bL[KNB];
#pragma unroll
    for (int k = 0; k < KNB; ++k) {
        int j = __shfl(jl, k);
        bL[k] = P32[(size_t)j * 128 + 64 + lane];
    }

    // own A row + replicated-W2 B-frags (cache-hot)
    frag_u fA[4]; fragAB fW[4];
    const unsigned short* An = Ab + (size_t)n * DIM;
#pragma unroll
    for (int ks = 0; ks < 4; ++ks) {
        fA[ks].s = *(const fragAB*)(An + ks * 32 + lg * 8);
        fW[ks]   = *(const fragAB*)(W2b + ks * 32 + lg * 8);
    }

    // H build (bf16, trunc pack) + MFMA score chain
    f32x4 accS = (f32x4){0.f, 0.f, 0.f, 0.f};
#pragma unroll
    for (int ks = 0; ks < 4; ++ks) {
        u32x4 alo = fA[ks].u << 16, ahi = fA[ks].u & 0xffff0000u;
        u32x4 blo = fB[ks].u << 16, bhi = fB[ks].u & 0xffff0000u;
        frag_u h;
#pragma unroll
        for (int p = 0; p < 4; ++p) {
            float h0 = fmaxf(__uint_as_float(alo[p]) + __uint_as_float(blo[p]), 0.f);
            float h1 = fmaxf(__uint_as_float(ahi[p]) + __uint_as_float(bhi[p]), 0.f);
            h.u[p] = (__float_as_uint(h0) >> 16) | (__float_as_uint(h1) & 0xffff0000u);
        }
        accS = __builtin_amdgcn_mfma_f32_16x16x32_bf16(h.s, fW[ks], accS, 0, 0, 0);
    }
    // lane holds S[lg*4+r] in accS[r] (replicated across lr)

    // softmax: global max, 4 exps per lane, distribute e across lg groups
    float m = fmaxf(fmaxf(accS[0], accS[1]), fmaxf(accS[2], accS[3]));
    m = fmaxf(m, __shfl_xor(m, 16));
    m = fmaxf(m, __shfl_xor(m, 32));

    float e4[4];
#pragma unroll
    for (int r = 0; r < 4; ++r) e4[r] = __expf(accS[r] - m);

    float sum = e4[0] + e4[1] + e4[2] + e4[3];
    sum += __shfl_xor(sum, 16);
    sum += __shfl_xor(sum, 32);
    const float inv = 1.f / sum;

    const bool hi1 = lg & 1, hi2 = lg & 2;
    float o4[4];
#pragma unroll
    for (int r = 0; r < 4; ++r) o4[r] = __shfl_xor(e4[r], 16);
    float v8[8];
#pragma unroll
    for (int r = 0; r < 4; ++r) {
        v8[r]     = hi1 ? o4[r] : e4[r];
        v8[4 + r] = hi1 ? e4[r] : o4[r];
    }
    float o8[8];
#pragma unroll
    for (int i = 0; i < 8; ++i) o8[i] = __shfl_xor(v8[i], 32);
    float e[KNB];
#pragma unroll
    for (int i = 0; i < 8; ++i) {
        e[i]     = hi2 ? o8[i] : v8[i];
        e[8 + i] = hi2 ? v8[i] : o8[i];
    }

    // weighted aggregation
    float o0 = 0.f, o1 = 0.f;
#pragma unroll
    for (int k = 0; k < KNB; ++k) {
        o0 += e[k] * bflo(bL[k]);
        o1 += e[k] * bfhi(bL[k]);
    }

    float2 o; o.x = o0 * inv; o.y = o1 * inv;
    *(float2*)(out + (size_t)n * DIM + 2 * lane) = o;
}

// ---------------------------------------------------------------------------
// Fallback (workspace too small): direct computation, one wave/node.
// ---------------------------------------------------------------------------
__global__ __launch_bounds__(256) void na_naive(
    const float* __restrict__ lat, const int* __restrict__ nbr,
    const float* __restrict__ W1, const float* __restrict__ b1,
    const float* __restrict__ W2, float* __restrict__ out, int nNodes)
{
    const int wave = threadIdx.x >> 6;
    const int lane = threadIdx.x & 63;
    const int n = blockIdx.x * 4 + wave;
    if (n >= nNodes) return;

    const int d0 = lane, d1 = lane + 64;
    const float w20 = W2[d0];
    const float w21 = W2[d1];
    const float c0 = lat[(size_t)n * DIM + d0];
    const float c1 = lat[(size_t)n * DIM + d1];

    float a0 = b1[d0], a1 = b1[d1];
    for (int r = 0; r < DIM; ++r) {
        float cv = (r < 64) ? __shfl(c0, r) : __shfl(c1, r - 64);
        a0 += cv * W1[(size_t)r * DIM + d0];
        a1 += cv * W1[(size_t)r * DIM + d1];
    }

    const int jl = nbr[n * KNB + (lane & 15)];
    float s[KNB], nl0[KNB], nl1[KNB];

    for (int k = 0; k < KNB; ++k) {
        int j = __shfl(jl, k);
        float l0 = lat[(size_t)j * DIM + d0];
        float l1 = lat[(size_t)j * DIM + d1];
        nl0[k] = l0; nl1[k] = l1;
        float h0 = a0, h1 = a1;
        for (int r = 0; r < DIM; ++r) {
            float nv = (r < 64) ? __shfl(l0, r) : __shfl(l1, r - 64);
            h0 += nv * W1[(size_t)(DIM + r) * DIM + d0];
            h1 += nv * W1[(size_t)(DIM + r) * DIM + d1];
        }
        h0 = fmaxf(h0, 0.f);
        h1 = fmaxf(h1, 0.f);
        float p = h0 * w20 + h1 * w21;
#pragma unroll
        for (int off = 32; off; off >>= 1) p += __shfl_xor(p, off);
        s[k] = p;
    }

    float m = s[0];
#pragma unroll
    for (int k = 1; k < KNB; ++k) m = fmaxf(m, s[k]);
    float sum = 0.f;
#pragma unroll
    for (int k = 0; k < KNB; ++k) { s[k] = expf(s[k] - m); sum += s[k]; }
    float inv = 1.f / sum;

    float o0 = 0.f, o1 = 0.f;
#pragma unroll
    for (int k = 0; k < KNB; ++k) { o0 += s[k] * nl0[k]; o1 += s[k] * nl1[k]; }

    out[(size_t)n * DIM + d0] = o0 * inv;
    out[(size_t)n * DIM + d1] = o1 * inv;
}

extern "C" void kernel_launch(void* const* d_in, const int* in_sizes, int n_in,
                              void* d_out, int out_size, void* d_ws, size_t ws_size,
                              hipStream_t stream)
{
    const float* lat = (const float*)d_in[0];
    const int*   nbr = (const int*)  d_in[1];
    const float* W1  = (const float*)d_in[2];
    const float* b1  = (const float*)d_in[3];
    const float* W2  = (const float*)d_in[4];
    // d_in[5] = b2: shift-invariant under softmax, unused.
    float* out = (float*)d_out;

    const int nNodes = in_sizes[0] / DIM;  // 100000
    const size_t bytesAb = (size_t)nNodes * DIM * sizeof(unsigned short); // 25.6 MB
    const size_t bytesP  = (size_t)nNodes * 256 * sizeof(unsigned short); // 51.2 MB
    const size_t bytesW  = (256 * DIM + DIM) * sizeof(unsigned short);    // 64.25 KiB

    if (ws_size >= bytesAb + bytesP + bytesW) {
        unsigned short* Ab  = (unsigned short*)d_ws;
        unsigned short* P   = (unsigned short*)((char*)d_ws + bytesAb);
        unsigned short* W1T = (unsigned short*)((char*)d_ws + bytesAb + bytesP);
        unsigned short* W2b = W1T + 256 * DIM;
        na_w1t<<<128, 256, 0, stream>>>(W1, W2, W1T, W2b);
        na_precompute_mfma<<<(nNodes + 63) / 64, 256, 0, stream>>>(lat, W1T, b1, Ab, P, nNodes);
        na_score_agg<<<(nNodes + 3) / 4, 256, 0, stream>>>(nbr, Ab, P, (const unsigned int*)P, W2b, out, nNodes);
    } else {
        na_naive<<<(nNodes + 3) / 4, 256, 0, stream>>>(lat, nbr, W1, b1, W2, out, nNodes);
    }
}

// Round 5
// 192.041 us; speedup vs baseline: 2.9935x; 1.0529x over previous
//
#include <hip/hip_runtime.h>
#include <hip/hip_bf16.h>

#define DIM 128
#define KNB 16

using fragAB = __attribute__((ext_vector_type(8))) short;   // 8 bf16 (4 VGPRs)
using f32x4  = __attribute__((ext_vector_type(4))) float;   // 4 fp32 acc
using u32x4  = __attribute__((ext_vector_type(4))) unsigned int;

union frag_u { fragAB s; u32x4 u; };

__device__ __forceinline__ unsigned short bf16bits(float f) {
    union { float f; unsigned u; } v; v.f = f;
    unsigned r = v.u + 0x7fffu + ((v.u >> 16) & 1u);   // round-nearest-even
    return (unsigned short)(r >> 16);
}
__device__ __forceinline__ float bflo(unsigned u) { return __uint_as_float(u << 16); }
__device__ __forceinline__ float bfhi(unsigned u) { return __uint_as_float(u & 0xffff0000u); }

// ---------------------------------------------------------------------------
// W1T pack (bf16) + W2 bf16. W1T[h'][d]: h'<128 -> W1[d][h'] (A-part),
// h'>=128 -> W1[128+d][h'-128] (B-part).
// ---------------------------------------------------------------------------
__global__ __launch_bounds__(256) void na_w1t(
    const float* __restrict__ W1, const float* __restrict__ W2,
    unsigned short* __restrict__ W1T, unsigned short* __restrict__ W2b)
{
    int idx = blockIdx.x * 256 + threadIdx.x;   // 0..32767 = h'*128 + d
    int hp = idx >> 7, d = idx & 127;
    float v = (hp < DIM) ? W1[(size_t)d * DIM + hp]
                         : W1[(size_t)(DIM + d) * DIM + (hp - DIM)];
    W1T[idx] = bf16bits(v);
    if (blockIdx.x == 0 && threadIdx.x < DIM) W2b[threadIdx.x] = bf16bits(W2[threadIdx.x]);
}

// ---------------------------------------------------------------------------
// Phase 1 (MFMA, SWAPPED operands): D = W1tile(16 h' x K) . latT(K x 16 nodes)
//   => D col (lane&15)  = node   (mbase+lr)
//      D row (lg*4+reg) = h'     (nt*16+lg*4+r)  -> 4 CONSECUTIVE h' per lane
// Epilogue: pack 4 bf16 -> 8B vector store per nt (16 stores/wave, natural
// order). lat-half of P written from the held B-frags (bl), no re-read.
//   Ab[n][h]      = bf16( b1[h] + lat[n]·W1top[:,h] )
//   P[n][0..128)  = bf16( lat[n]·W1bot[:,h] )
//   P[n][128..256)= bf16( lat[n] )
// ---------------------------------------------------------------------------
__global__ __launch_bounds__(256) void na_precompute_mfma(
    const float* __restrict__ lat, const unsigned short* __restrict__ W1T,
    const float* __restrict__ b1, unsigned short* __restrict__ Ab,
    unsigned short* __restrict__ P, int nNodes)
{
    const int wave = threadIdx.x >> 6;
    const int lane = threadIdx.x & 63;
    const int lg = lane >> 4, lr = lane & 15;
    const int mbase = blockIdx.x * 64 + wave * 16;

    f32x4 acc[16];
#pragma unroll
    for (int i = 0; i < 16; ++i) acc[i] = (f32x4){0.f, 0.f, 0.f, 0.f};

    const int nrow = mbase + lr;                // this lane's node
    const bool avalid = nrow < nNodes;
    const int arc = avalid ? nrow : (nNodes - 1);
    const float* lptr = lat + (size_t)arc * DIM;

    fragAB bl[4];                               // lat row chunks (B-operand)
#pragma unroll
    for (int ks = 0; ks < 4; ++ks) {
        f32x4 lo = *(const f32x4*)(lptr + ks * 32 + lg * 8);
        f32x4 hi = *(const f32x4*)(lptr + ks * 32 + lg * 8 + 4);
#pragma unroll
        for (int j = 0; j < 4; ++j) {
            bl[ks][j]     = (short)bf16bits(lo[j]);
            bl[ks][4 + j] = (short)bf16bits(hi[j]);
        }
#pragma unroll
        for (int nt = 0; nt < 16; ++nt) {
            const unsigned short* wp = W1T + (size_t)(nt * 16 + lr) * DIM + ks * 32 + lg * 8;
            fragAB af = *(const fragAB*)wp;     // A-operand: W1T rows (L1-hot)
            acc[nt] = __builtin_amdgcn_mfma_f32_16x16x32_bf16(af, bl[ks], acc[nt], 0, 0, 0);
        }
    }

    if (avalid) {
        unsigned short* arow = Ab + (size_t)nrow * DIM;
        unsigned short* prow = P  + (size_t)nrow * 256;
#pragma unroll
        for (int nt = 0; nt < 8; ++nt) {        // A-half, +bias
            float4 bv = *(const float4*)(b1 + nt * 16 + lg * 4);
            uint2 pk;
            pk.x = (unsigned)bf16bits(acc[nt][0] + bv.x) | ((unsigned)bf16bits(acc[nt][1] + bv.y) << 16);
            pk.y = (unsigned)bf16bits(acc[nt][2] + bv.z) | ((unsigned)bf16bits(acc[nt][3] + bv.w) << 16);
            *(uint2*)(arow + nt * 16 + lg * 4) = pk;
        }
#pragma unroll
        for (int nt = 8; nt < 16; ++nt) {       // B-half of P
            uint2 pk;
            pk.x = (unsigned)bf16bits(acc[nt][0]) | ((unsigned)bf16bits(acc[nt][1]) << 16);
            pk.y = (unsigned)bf16bits(acc[nt][2]) | ((unsigned)bf16bits(acc[nt][3]) << 16);
            *(uint2*)(prow + (nt - 8) * 16 + lg * 4) = pk;
        }
#pragma unroll
        for (int ks = 0; ks < 4; ++ks)          // lat-half of P from bl frags
            *(fragAB*)(prow + DIM + ks * 32 + lg * 8) = bl[ks];
    }
}

// ---------------------------------------------------------------------------
// Phase 2: one wave per node. Scores via MFMA (W2 replicated over B-cols),
// exp 4/lane + butterfly distribution, weighted aggregation of lat rows.
// ---------------------------------------------------------------------------
__global__ __launch_bounds__(256) void na_score_agg(
    const int* __restrict__ nbr, const unsigned short* __restrict__ Ab,
    const unsigned short* __restrict__ Pu, const unsigned int* __restrict__ P32,
    const unsigned short* __restrict__ W2b, float* __restrict__ out, int nNodes)
{
    const int wave = threadIdx.x >> 6;
    const int lane = threadIdx.x & 63;
    const int lg = lane >> 4, lr = lane & 15;
    const int n = blockIdx.x * 4 + wave;
    if (n >= nNodes) return;

    const int jl = nbr[n * KNB + lr];          // lane's neighbor (k = lr)

    // B-half gathers: lane reads 16B of row j_lr per ks (A-frag layout for H)
    frag_u fB[4];
    const unsigned short* Pj = Pu + (size_t)jl * 256;
#pragma unroll
    for (int ks = 0; ks < 4; ++ks)
        fB[ks].s = *(const fragAB*)(Pj + ks * 32 + lg * 8);

    // lat-half gathers: lane owns dims (2l,2l+1), loop over k
    unsigned bL[KNB];
#pragma unroll
    for (int k = 0; k < KNB; ++k) {
        int j = __shfl(jl, k);
        bL[k] = P32[(size_t)j * 128 + 64 + lane];
    }

    // own A row + replicated-W2 B-frags (cache-hot)
    frag_u fA[4]; fragAB fW[4];
    const unsigned short* An = Ab + (size_t)n * DIM;
#pragma unroll
    for (int ks = 0; ks < 4; ++ks) {
        fA[ks].s = *(const fragAB*)(An + ks * 32 + lg * 8);
        fW[ks]   = *(const fragAB*)(W2b + ks * 32 + lg * 8);
    }

    // H build (bf16, trunc pack) + MFMA score chain
    f32x4 accS = (f32x4){0.f, 0.f, 0.f, 0.f};
#pragma unroll
    for (int ks = 0; ks < 4; ++ks) {
        u32x4 alo = fA[ks].u << 16, ahi = fA[ks].u & 0xffff0000u;
        u32x4 blo = fB[ks].u << 16, bhi = fB[ks].u & 0xffff0000u;
        frag_u h;
#pragma unroll
        for (int p = 0; p < 4; ++p) {
            float h0 = fmaxf(__uint_as_float(alo[p]) + __uint_as_float(blo[p]), 0.f);
            float h1 = fmaxf(__uint_as_float(ahi[p]) + __uint_as_float(bhi[p]), 0.f);
            h.u[p] = (__float_as_uint(h0) >> 16) | (__float_as_uint(h1) & 0xffff0000u);
        }
        accS = __builtin_amdgcn_mfma_f32_16x16x32_bf16(h.s, fW[ks], accS, 0, 0, 0);
    }
    // lane holds S[lg*4+r] in accS[r] (replicated across lr)

    // softmax: global max, 4 exps per lane, distribute e across lg groups
    float m = fmaxf(fmaxf(accS[0], accS[1]), fmaxf(accS[2], accS[3]));
    m = fmaxf(m, __shfl_xor(m, 16));
    m = fmaxf(m, __shfl_xor(m, 32));

    float e4[4];
#pragma unroll
    for (int r = 0; r < 4; ++r) e4[r] = __expf(accS[r] - m);

    float sum = e4[0] + e4[1] + e4[2] + e4[3];
    sum += __shfl_xor(sum, 16);
    sum += __shfl_xor(sum, 32);
    const float inv = 1.f / sum;

    const bool hi1 = lg & 1, hi2 = lg & 2;
    float o4[4];
#pragma unroll
    for (int r = 0; r < 4; ++r) o4[r] = __shfl_xor(e4[r], 16);
    float v8[8];
#pragma unroll
    for (int r = 0; r < 4; ++r) {
        v8[r]     = hi1 ? o4[r] : e4[r];
        v8[4 + r] = hi1 ? e4[r] : o4[r];
    }
    float o8[8];
#pragma unroll
    for (int i = 0; i < 8; ++i) o8[i] = __shfl_xor(v8[i], 32);
    float e[KNB];
#pragma unroll
    for (int i = 0; i < 8; ++i) {
        e[i]     = hi2 ? o8[i] : v8[i];
        e[8 + i] = hi2 ? v8[i] : o8[i];
    }

    // weighted aggregation
    float o0 = 0.f, o1 = 0.f;
#pragma unroll
    for (int k = 0; k < KNB; ++k) {
        o0 += e[k] * bflo(bL[k]);
        o1 += e[k] * bfhi(bL[k]);
    }

    float2 o; o.x = o0 * inv; o.y = o1 * inv;
    *(float2*)(out + (size_t)n * DIM + 2 * lane) = o;
}

// ---------------------------------------------------------------------------
// Fallback (workspace too small): direct computation, one wave/node.
// ---------------------------------------------------------------------------
__global__ __launch_bounds__(256) void na_naive(
    const float* __restrict__ lat, const int* __restrict__ nbr,
    const float* __restrict__ W1, const float* __restrict__ b1,
    const float* __restrict__ W2, float* __restrict__ out, int nNodes)
{
    const int wave = threadIdx.x >> 6;
    const int lane = threadIdx.x & 63;
    const int n = blockIdx.x * 4 + wave;
    if (n >= nNodes) return;

    const int d0 = lane, d1 = lane + 64;
    const float w20 = W2[d0];
    const float w21 = W2[d1];
    const float c0 = lat[(size_t)n * DIM + d0];
    const float c1 = lat[(size_t)n * DIM + d1];

    float a0 = b1[d0], a1 = b1[d1];
    for (int r = 0; r < DIM; ++r) {
        float cv = (r < 64) ? __shfl(c0, r) : __shfl(c1, r - 64);
        a0 += cv * W1[(size_t)r * DIM + d0];
        a1 += cv * W1[(size_t)r * DIM + d1];
    }

    const int jl = nbr[n * KNB + (lane & 15)];
    float s[KNB], nl0[KNB], nl1[KNB];

    for (int k = 0; k < KNB; ++k) {
        int j = __shfl(jl, k);
        float l0 = lat[(size_t)j * DIM + d0];
        float l1 = lat[(size_t)j * DIM + d1];
        nl0[k] = l0; nl1[k] = l1;
        float h0 = a0, h1 = a1;
        for (int r = 0; r < DIM; ++r) {
            float nv = (r < 64) ? __shfl(l0, r) : __shfl(l1, r - 64);
            h0 += nv * W1[(size_t)(DIM + r) * DIM + d0];
            h1 += nv * W1[(size_t)(DIM + r) * DIM + d1];
        }
        h0 = fmaxf(h0, 0.f);
        h1 = fmaxf(h1, 0.f);
        float p = h0 * w20 + h1 * w21;
#pragma unroll
        for (int off = 32; off; off >>= 1) p += __shfl_xor(p, off);
        s[k] = p;
    }

    float m = s[0];
#pragma unroll
    for (int k = 1; k < KNB; ++k) m = fmaxf(m, s[k]);
    float sum = 0.f;
#pragma unroll
    for (int k = 0; k < KNB; ++k) { s[k] = expf(s[k] - m); sum += s[k]; }
    float inv = 1.f / sum;

    float o0 = 0.f, o1 = 0.f;
#pragma unroll
    for (int k = 0; k < KNB; ++k) { o0 += s[k] * nl0[k]; o1 += s[k] * nl1[k]; }

    out[(size_t)n * DIM + d0] = o0 * inv;
    out[(size_t)n * DIM + d1] = o1 * inv;
}

extern "C" void kernel_launch(void* const* d_in, const int* in_sizes, int n_in,
                              void* d_out, int out_size, void* d_ws, size_t ws_size,
                              hipStream_t stream)
{
    const float* lat = (const float*)d_in[0];
    const int*   nbr = (const int*)  d_in[1];
    const float* W1  = (const float*)d_in[2];
    const float* b1  = (const float*)d_in[3];
    const float* W2  = (const float*)d_in[4];
    // d_in[5] = b2: shift-invariant under softmax, unused.
    float* out = (float*)d_out;

    const int nNodes = in_sizes[0] / DIM;  // 100000
    const size_t bytesAb = (size_t)nNodes * DIM * sizeof(unsigned short); // 25.6 MB
    const size_t bytesP  = (size_t)nNodes * 256 * sizeof(unsigned short); // 51.2 MB
    const size_t bytesW  = (256 * DIM + DIM) * sizeof(unsigned short);    // 64.25 KiB

    if (ws_size >= bytesAb + bytesP + bytesW) {
        unsigned short* Ab  = (unsigned short*)d_ws;
        unsigned short* P   = (unsigned short*)((char*)d_ws + bytesAb);
        unsigned short* W1T = (unsigned short*)((char*)d_ws + bytesAb + bytesP);
        unsigned short* W2b = W1T + 256 * DIM;
        na_w1t<<<128, 256, 0, stream>>>(W1, W2, W1T, W2b);
        na_precompute_mfma<<<(nNodes + 63) / 64, 256, 0, stream>>>(lat, W1T, b1, Ab, P, nNodes);
        na_score_agg<<<(nNodes + 3) / 4, 256, 0, stream>>>(nbr, Ab, P, (const unsigned int*)P, W2b, out, nNodes);
    } else {
        na_naive<<<(nNodes + 3) / 4, 256, 0, stream>>>(lat, nbr, W1, b1, W2, out, nNodes);
    }
}

// Round 6
// 189.407 us; speedup vs baseline: 3.0351x; 1.0139x over previous
//
#include <hip/hip_runtime.h>
#include <hip/hip_bf16.h>

#define DIM 128
#define KNB 16

using fragAB = __attribute__((ext_vector_type(8))) short;   // 8 bf16 (4 VGPRs)
using f32x4  = __attribute__((ext_vector_type(4))) float;   // 4 fp32 acc
using u32x4  = __attribute__((ext_vector_type(4))) unsigned int;

union frag_u { fragAB s; u32x4 u; };

__device__ __forceinline__ unsigned short bf16bits(float f) {
    union { float f; unsigned u; } v; v.f = f;
    unsigned r = v.u + 0x7fffu + ((v.u >> 16) & 1u);   // round-nearest-even
    return (unsigned short)(r >> 16);
}
__device__ __forceinline__ float bflo(unsigned u) { return __uint_as_float(u << 16); }
__device__ __forceinline__ float bfhi(unsigned u) { return __uint_as_float(u & 0xffff0000u); }

// ---------------------------------------------------------------------------
// W1T pack (bf16) + W2 bf16. W1T[h'][d]: h'<128 -> W1[d][h'] (A-part),
// h'>=128 -> W1[128+d][h'-128] (B-part).
// ---------------------------------------------------------------------------
__global__ __launch_bounds__(256) void na_w1t(
    const float* __restrict__ W1, const float* __restrict__ W2,
    unsigned short* __restrict__ W1T, unsigned short* __restrict__ W2b)
{
    int idx = blockIdx.x * 256 + threadIdx.x;   // 0..32767 = h'*128 + d
    int hp = idx >> 7, d = idx & 127;
    float v = (hp < DIM) ? W1[(size_t)d * DIM + hp]
                         : W1[(size_t)(DIM + d) * DIM + (hp - DIM)];
    W1T[idx] = bf16bits(v);
    if (blockIdx.x == 0 && threadIdx.x < DIM) W2b[threadIdx.x] = bf16bits(W2[threadIdx.x]);
}

// ---------------------------------------------------------------------------
// Phase 1 (MFMA, swapped operands, 32 rows/wave): two B-frag node-sets share
// each W1T A-frag load -> W1T L2 traffic halved, 1 load : 2 MFMA.
//   D = W1tile(16 h' x K) . latT(K x 16 nodes); D col = node, row = h'.
//   Ab[n][h]      = bf16( b1[h] + lat[n]·W1top[:,h] )
//   P[n][0..128)  = bf16( lat[n]·W1bot[:,h] )
//   P[n][128..256)= bf16( lat[n] )   <- from held B-frags, no re-read
// ---------------------------------------------------------------------------
__global__ __launch_bounds__(256) void na_precompute_mfma(
    const float* __restrict__ lat, const unsigned short* __restrict__ W1T,
    const float* __restrict__ b1, unsigned short* __restrict__ Ab,
    unsigned short* __restrict__ P, int nNodes)
{
    const int wave = threadIdx.x >> 6;
    const int lane = threadIdx.x & 63;
    const int lg = lane >> 4, lr = lane & 15;
    const int mbase = blockIdx.x * 128 + wave * 32;

    f32x4 acc0[16], acc1[16];
#pragma unroll
    for (int i = 0; i < 16; ++i) {
        acc0[i] = (f32x4){0.f, 0.f, 0.f, 0.f};
        acc1[i] = (f32x4){0.f, 0.f, 0.f, 0.f};
    }

    const int r0 = mbase + lr;
    const int r1 = mbase + 16 + lr;
    const bool v0 = r0 < nNodes, v1 = r1 < nNodes;
    const float* p0 = lat + (size_t)(v0 ? r0 : (nNodes - 1)) * DIM;
    const float* p1 = lat + (size_t)(v1 ? r1 : (nNodes - 1)) * DIM;

    fragAB bl0[4], bl1[4];
#pragma unroll
    for (int ks = 0; ks < 4; ++ks) {
        f32x4 lo0 = *(const f32x4*)(p0 + ks * 32 + lg * 8);
        f32x4 hi0 = *(const f32x4*)(p0 + ks * 32 + lg * 8 + 4);
        f32x4 lo1 = *(const f32x4*)(p1 + ks * 32 + lg * 8);
        f32x4 hi1 = *(const f32x4*)(p1 + ks * 32 + lg * 8 + 4);
#pragma unroll
        for (int j = 0; j < 4; ++j) {
            bl0[ks][j]     = (short)bf16bits(lo0[j]);
            bl0[ks][4 + j] = (short)bf16bits(hi0[j]);
            bl1[ks][j]     = (short)bf16bits(lo1[j]);
            bl1[ks][4 + j] = (short)bf16bits(hi1[j]);
        }
    }

#pragma unroll
    for (int ks = 0; ks < 4; ++ks) {
#pragma unroll
        for (int nt = 0; nt < 16; ++nt) {
            fragAB af = *(const fragAB*)(W1T + (size_t)(nt * 16 + lr) * DIM + ks * 32 + lg * 8);
            acc0[nt] = __builtin_amdgcn_mfma_f32_16x16x32_bf16(af, bl0[ks], acc0[nt], 0, 0, 0);
            acc1[nt] = __builtin_amdgcn_mfma_f32_16x16x32_bf16(af, bl1[ks], acc1[nt], 0, 0, 0);
        }
    }

    if (v0) {
        unsigned short* arow = Ab + (size_t)r0 * DIM;
        unsigned short* prow = P  + (size_t)r0 * 256;
#pragma unroll
        for (int nt = 0; nt < 8; ++nt) {
            float4 bv = *(const float4*)(b1 + nt * 16 + lg * 4);
            uint2 pk;
            pk.x = (unsigned)bf16bits(acc0[nt][0] + bv.x) | ((unsigned)bf16bits(acc0[nt][1] + bv.y) << 16);
            pk.y = (unsigned)bf16bits(acc0[nt][2] + bv.z) | ((unsigned)bf16bits(acc0[nt][3] + bv.w) << 16);
            *(uint2*)(arow + nt * 16 + lg * 4) = pk;
        }
#pragma unroll
        for (int nt = 8; nt < 16; ++nt) {
            uint2 pk;
            pk.x = (unsigned)bf16bits(acc0[nt][0]) | ((unsigned)bf16bits(acc0[nt][1]) << 16);
            pk.y = (unsigned)bf16bits(acc0[nt][2]) | ((unsigned)bf16bits(acc0[nt][3]) << 16);
            *(uint2*)(prow + (nt - 8) * 16 + lg * 4) = pk;
        }
#pragma unroll
        for (int ks = 0; ks < 4; ++ks)
            *(fragAB*)(prow + DIM + ks * 32 + lg * 8) = bl0[ks];
    }
    if (v1) {
        unsigned short* arow = Ab + (size_t)r1 * DIM;
        unsigned short* prow = P  + (size_t)r1 * 256;
#pragma unroll
        for (int nt = 0; nt < 8; ++nt) {
            float4 bv = *(const float4*)(b1 + nt * 16 + lg * 4);
            uint2 pk;
            pk.x = (unsigned)bf16bits(acc1[nt][0] + bv.x) | ((unsigned)bf16bits(acc1[nt][1] + bv.y) << 16);
            pk.y = (unsigned)bf16bits(acc1[nt][2] + bv.z) | ((unsigned)bf16bits(acc1[nt][3] + bv.w) << 16);
            *(uint2*)(arow + nt * 16 + lg * 4) = pk;
        }
#pragma unroll
        for (int nt = 8; nt < 16; ++nt) {
            uint2 pk;
            pk.x = (unsigned)bf16bits(acc1[nt][0]) | ((unsigned)bf16bits(acc1[nt][1]) << 16);
            pk.y = (unsigned)bf16bits(acc1[nt][2]) | ((unsigned)bf16bits(acc1[nt][3]) << 16);
            *(uint2*)(prow + (nt - 8) * 16 + lg * 4) = pk;
        }
#pragma unroll
        for (int ks = 0; ks < 4; ++ks)
            *(fragAB*)(prow + DIM + ks * 32 + lg * 8) = bl1[ks];
    }
}

// ---------------------------------------------------------------------------
// Phase 2 helpers
// ---------------------------------------------------------------------------
__device__ __forceinline__ f32x4 score4(const frag_u* fA, const frag_u* fB, const fragAB* fW)
{
    f32x4 accS = (f32x4){0.f, 0.f, 0.f, 0.f};
#pragma unroll
    for (int ks = 0; ks < 4; ++ks) {
        u32x4 alo = fA[ks].u << 16, ahi = fA[ks].u & 0xffff0000u;
        u32x4 blo = fB[ks].u << 16, bhi = fB[ks].u & 0xffff0000u;
        frag_u h;
#pragma unroll
        for (int p = 0; p < 4; ++p) {
            float h0 = fmaxf(__uint_as_float(alo[p]) + __uint_as_float(blo[p]), 0.f);
            float h1 = fmaxf(__uint_as_float(ahi[p]) + __uint_as_float(bhi[p]), 0.f);
            h.u[p] = (__float_as_uint(h0) >> 16) | (__float_as_uint(h1) & 0xffff0000u);
        }
        accS = __builtin_amdgcn_mfma_f32_16x16x32_bf16(h.s, fW[ks], accS, 0, 0, 0);
    }
    return accS;   // lane holds S[lg*4+r] (replicated across lr)
}

__device__ __forceinline__ float2 softmax_agg(f32x4 accS, const unsigned* bL, int lg)
{
    float m = fmaxf(fmaxf(accS[0], accS[1]), fmaxf(accS[2], accS[3]));
    m = fmaxf(m, __shfl_xor(m, 16));
    m = fmaxf(m, __shfl_xor(m, 32));

    float e4[4];
#pragma unroll
    for (int r = 0; r < 4; ++r) e4[r] = __expf(accS[r] - m);

    float sum = e4[0] + e4[1] + e4[2] + e4[3];
    sum += __shfl_xor(sum, 16);
    sum += __shfl_xor(sum, 32);
    const float inv = 1.f / sum;

    const bool hi1 = lg & 1, hi2 = lg & 2;
    float o4[4];
#pragma unroll
    for (int r = 0; r < 4; ++r) o4[r] = __shfl_xor(e4[r], 16);
    float v8[8];
#pragma unroll
    for (int r = 0; r < 4; ++r) {
        v8[r]     = hi1 ? o4[r] : e4[r];
        v8[4 + r] = hi1 ? e4[r] : o4[r];
    }
    float o8[8];
#pragma unroll
    for (int i = 0; i < 8; ++i) o8[i] = __shfl_xor(v8[i], 32);
    float e[KNB];
#pragma unroll
    for (int i = 0; i < 8; ++i) {
        e[i]     = hi2 ? o8[i] : v8[i];
        e[8 + i] = hi2 ? v8[i] : o8[i];
    }

    float o0 = 0.f, o1 = 0.f;
#pragma unroll
    for (int k = 0; k < KNB; ++k) {
        o0 += e[k] * bflo(bL[k]);
        o1 += e[k] * bfhi(bL[k]);
    }
    float2 o; o.x = o0 * inv; o.y = o1 * inv;
    return o;
}

// ---------------------------------------------------------------------------
// Phase 2: TWO nodes per wave; all gathers for both nodes issued before any
// compute (doubles per-wave memory-level parallelism). Scores via MFMA,
// butterfly exp distribution, weighted aggregation.
// ---------------------------------------------------------------------------
__global__ __launch_bounds__(256) void na_score_agg(
    const int* __restrict__ nbr, const unsigned short* __restrict__ Ab,
    const unsigned short* __restrict__ Pu, const unsigned int* __restrict__ P32,
    const unsigned short* __restrict__ W2b, float* __restrict__ out, int nNodes)
{
    const int wave = threadIdx.x >> 6;
    const int lane = threadIdx.x & 63;
    const int lg = lane >> 4, lr = lane & 15;
    const int n0 = (blockIdx.x * 4 + wave) * 2;
    if (n0 >= nNodes) return;
    const int n1 = n0 + 1;
    const bool has1 = n1 < nNodes;
    const int n1c = has1 ? n1 : n0;

    const int jl0 = nbr[n0  * KNB + lr];
    const int jl1 = nbr[n1c * KNB + lr];

    // ---- issue ALL gathers up front ----
    frag_u fB0[4], fB1[4];
    const unsigned short* Pj0 = Pu + (size_t)jl0 * 256;
    const unsigned short* Pj1 = Pu + (size_t)jl1 * 256;
#pragma unroll
    for (int ks = 0; ks < 4; ++ks) {
        fB0[ks].s = *(const fragAB*)(Pj0 + ks * 32 + lg * 8);
        fB1[ks].s = *(const fragAB*)(Pj1 + ks * 32 + lg * 8);
    }
    unsigned bL0[KNB], bL1[KNB];
#pragma unroll
    for (int k = 0; k < KNB; ++k) {
        int j0 = __shfl(jl0, k);
        int j1 = __shfl(jl1, k);
        bL0[k] = P32[(size_t)j0 * 128 + 64 + lane];
        bL1[k] = P32[(size_t)j1 * 128 + 64 + lane];
    }

    frag_u fA0[4], fA1[4]; fragAB fW[4];
    const unsigned short* An0 = Ab + (size_t)n0  * DIM;
    const unsigned short* An1 = Ab + (size_t)n1c * DIM;
#pragma unroll
    for (int ks = 0; ks < 4; ++ks) {
        fA0[ks].s = *(const fragAB*)(An0 + ks * 32 + lg * 8);
        fA1[ks].s = *(const fragAB*)(An1 + ks * 32 + lg * 8);
        fW[ks]    = *(const fragAB*)(W2b + ks * 32 + lg * 8);
    }

    // ---- compute ----
    f32x4 s0 = score4(fA0, fB0, fW);
    f32x4 s1 = score4(fA1, fB1, fW);

    float2 o0 = softmax_agg(s0, bL0, lg);
    float2 o1 = softmax_agg(s1, bL1, lg);

    *(float2*)(out + (size_t)n0 * DIM + 2 * lane) = o0;
    if (has1) *(float2*)(out + (size_t)n1 * DIM + 2 * lane) = o1;
}

// ---------------------------------------------------------------------------
// Fallback (workspace too small): direct computation, one wave/node.
// ---------------------------------------------------------------------------
__global__ __launch_bounds__(256) void na_naive(
    const float* __restrict__ lat, const int* __restrict__ nbr,
    const float* __restrict__ W1, const float* __restrict__ b1,
    const float* __restrict__ W2, float* __restrict__ out, int nNodes)
{
    const int wave = threadIdx.x >> 6;
    const int lane = threadIdx.x & 63;
    const int n = blockIdx.x * 4 + wave;
    if (n >= nNodes) return;

    const int d0 = lane, d1 = lane + 64;
    const float w20 = W2[d0];
    const float w21 = W2[d1];
    const float c0 = lat[(size_t)n * DIM + d0];
    const float c1 = lat[(size_t)n * DIM + d1];

    float a0 = b1[d0], a1 = b1[d1];
    for (int r = 0; r < DIM; ++r) {
        float cv = (r < 64) ? __shfl(c0, r) : __shfl(c1, r - 64);
        a0 += cv * W1[(size_t)r * DIM + d0];
        a1 += cv * W1[(size_t)r * DIM + d1];
    }

    const int jl = nbr[n * KNB + (lane & 15)];
    float s[KNB], nl0[KNB], nl1[KNB];

    for (int k = 0; k < KNB; ++k) {
        int j = __shfl(jl, k);
        float l0 = lat[(size_t)j * DIM + d0];
        float l1 = lat[(size_t)j * DIM + d1];
        nl0[k] = l0; nl1[k] = l1;
        float h0 = a0, h1 = a1;
        for (int r = 0; r < DIM; ++r) {
            float nv = (r < 64) ? __shfl(l0, r) : __shfl(l1, r - 64);
            h0 += nv * W1[(size_t)(DIM + r) * DIM + d0];
            h1 += nv * W1[(size_t)(DIM + r) * DIM + d1];
        }
        h0 = fmaxf(h0, 0.f);
        h1 = fmaxf(h1, 0.f);
        float p = h0 * w20 + h1 * w21;
#pragma unroll
        for (int off = 32; off; off >>= 1) p += __shfl_xor(p, off);
        s[k] = p;
    }

    float m = s[0];
#pragma unroll
    for (int k = 1; k < KNB; ++k) m = fmaxf(m, s[k]);
    float sum = 0.f;
#pragma unroll
    for (int k = 0; k < KNB; ++k) { s[k] = expf(s[k] - m); sum += s[k]; }
    float inv = 1.f / sum;

    float o0 = 0.f, o1 = 0.f;
#pragma unroll
    for (int k = 0; k < KNB; ++k) { o0 += s[k] * nl0[k]; o1 += s[k] * nl1[k]; }

    out[(size_t)n * DIM + d0] = o0 * inv;
    out[(size_t)n * DIM + d1] = o1 * inv;
}

extern "C" void kernel_launch(void* const* d_in, const int* in_sizes, int n_in,
                              void* d_out, int out_size, void* d_ws, size_t ws_size,
                              hipStream_t stream)
{
    const float* lat = (const float*)d_in[0];
    const int*   nbr = (const int*)  d_in[1];
    const float* W1  = (const float*)d_in[2];
    const float* b1  = (const float*)d_in[3];
    const float* W2  = (const float*)d_in[4];
    // d_in[5] = b2: shift-invariant under softmax, unused.
    float* out = (float*)d_out;

    const int nNodes = in_sizes[0] / DIM;  // 100000
    const size_t bytesAb = (size_t)nNodes * DIM * sizeof(unsigned short); // 25.6 MB
    const size_t bytesP  = (size_t)nNodes * 256 * sizeof(unsigned short); // 51.2 MB
    const size_t bytesW  = (256 * DIM + DIM) * sizeof(unsigned short);    // 64.25 KiB

    if (ws_size >= bytesAb + bytesP + bytesW) {
        unsigned short* Ab  = (unsigned short*)d_ws;
        unsigned short* P   = (unsigned short*)((char*)d_ws + bytesAb);
        unsigned short* W1T = (unsigned short*)((char*)d_ws + bytesAb + bytesP);
        unsigned short* W2b = W1T + 256 * DIM;
        na_w1t<<<128, 256, 0, stream>>>(W1, W2, W1T, W2b);
        na_precompute_mfma<<<(nNodes + 127) / 128, 256, 0, stream>>>(lat, W1T, b1, Ab, P, nNodes);
        na_score_agg<<<(nNodes + 7) / 8, 256, 0, stream>>>(nbr, Ab, P, (const unsigned int*)P, W2b, out, nNodes);
    } else {
        na_naive<<<(nNodes + 3) / 4, 256, 0, stream>>>(lat, nbr, W1, b1, W2, out, nNodes);
    }
}